// Round 21
// baseline (137.980 us; speedup 1.0000x reference)
//
#include <hip/hip_runtime.h>
#include <hip/hip_bf16.h>
#include <math.h>

typedef __bf16 bf16_t;
typedef __bf16 bf16x4_t __attribute__((ext_vector_type(4)));
typedef __bf16 bf16x8 __attribute__((ext_vector_type(8)));
typedef float f32x4 __attribute__((ext_vector_type(4)));
typedef unsigned long long u64;

typedef __attribute__((address_space(1))) const unsigned int cu32_g;
typedef __attribute__((address_space(3))) unsigned int u32_s;

#define NB 1024
#define NN 75
#define KF 512
#define F1 256
#define HSTR 100
#define ASTR 100

// ---------------------------------------------------------------------------
// Kernel 0: W [512][256] fp32 -> Wt [256][512] bf16 (unchanged, passing)
// ---------------------------------------------------------------------------
__global__ __launch_bounds__(256) void wt_kernel(const float* __restrict__ W,
                                                 bf16_t* __restrict__ Wt) {
    __shared__ float tile[64][65];
    const int kb = blockIdx.x * 64;
    const int nb = blockIdx.y * 64;
    const int tc = threadIdx.x & 63;
    const int tr = threadIdx.x >> 6;
#pragma unroll
    for (int r = tr; r < 64; r += 4)
        tile[r][tc] = W[(size_t)(kb + r) * F1 + nb + tc];
    __syncthreads();
#pragma unroll
    for (int r = tr; r < 64; r += 4)
        Wt[(size_t)(nb + r) * KF + kb + tc] = (bf16_t)tile[tc][r];
}

// ---------------------------------------------------------------------------
// Kernel 1: h = X @ W -> out[...,256:512].  PRODUCER/CONSUMER.
// 1200 blocks x 512 threads. Waves 4-7 = producers: stream X chunks
// (BK=64 fp32, 16KB) into ring-4 LDS via global_load_lds; publish chunk s-1
// after issuing s with counted vmcnt(4) (producer vmcnt = DMA only).
// Waves 0-3 = consumers: spin on ready flags, 2 MFMA K-steps per chunk
// (granule XOR swizzle per rule #21), W register-dbuf from L2-hot Wt.
// Flags: LDS atomics, acquire/release, workgroup scope. Monotonic ring.
// ---------------------------------------------------------------------------
__global__ __launch_bounds__(512, 4) void gemm_kernel(const float* __restrict__ X,
                                                      const bf16_t* __restrict__ Wt,
                                                      float* __restrict__ out) {
    __shared__ __align__(16) float Xs[4][64 * 64];   // ring-4 x 16 KB
    __shared__ int ready[4][4];   // [slot][producer] = published chunk seq
    __shared__ int done[4][4];    // [slot][consumer] = consumed chunk seq

    const int t = threadIdx.x;
    const int w = t >> 6;
    const int l = t & 63;
    const int lc = l & 15;
    const int lr = l >> 4;
    const int tile = blockIdx.x;
    const size_t rbase = (size_t)tile * 64;

    if (t < 16) { ready[t >> 2][t & 3] = -1; done[t >> 2][t & 3] = -1; }
    __syncthreads();   // flag init visible; ONLY block-wide barrier

    if (w >= 4) {
        // ================= PRODUCER p: rows p*16 .. p*16+15 =================
        const int p = w - 4;
        for (int s = 0; s < 8; ++s) {
            const int slot = s & 3;
            if (s >= 4) {   // wait until all consumers freed previous occupant
#pragma unroll
                for (int c = 0; c < 4; ++c)
                    while (__hip_atomic_load(&done[slot][c], __ATOMIC_ACQUIRE,
                                             __HIP_MEMORY_SCOPE_WORKGROUP) < s - 4) {}
            }
#pragma unroll
            for (int u = 0; u < 4; ++u) {
                const int row = p * 16 + u * 4 + (l >> 4);
                // logical granule (l&15)^(row&7) -> physical slot l&15 (rule #21)
                const float* g = X + (rbase + row) * KF + s * 64
                                 + (((l & 15) ^ (row & 7)) << 2);
                float* lp = &Xs[slot][(p * 16 + u * 4) * 64];
                __builtin_amdgcn_global_load_lds((cu32_g*)g, (u32_s*)lp, 16, 0, 0);
            }
            if (s > 0) {   // publish s-1: only the 4 loads of s still pending
                asm volatile("s_waitcnt vmcnt(4)" ::: "memory");
                __hip_atomic_store(&ready[(s - 1) & 3][p], s - 1,
                                   __ATOMIC_RELEASE, __HIP_MEMORY_SCOPE_WORKGROUP);
            }
        }
        asm volatile("s_waitcnt vmcnt(0)" ::: "memory");
        __hip_atomic_store(&ready[3][p], 7, __ATOMIC_RELEASE,
                           __HIP_MEMORY_SCOPE_WORKGROUP);
    } else {
        // ================= CONSUMER w: cols w*64 .. w*64+63 =================
        const bf16_t* wp0 = Wt + (size_t)(w * 64 +  0 + lc) * KF + lr * 8;
        const bf16_t* wp1 = Wt + (size_t)(w * 64 + 16 + lc) * KF + lr * 8;
        const bf16_t* wp2 = Wt + (size_t)(w * 64 + 32 + lc) * KF + lr * 8;
        const bf16_t* wp3 = Wt + (size_t)(w * 64 + 48 + lc) * KF + lr * 8;
        bf16x8 wA[4], wB[4];
#define WLOAD(WREG, KS)                                        \
        WREG[0] = *(const bf16x8*)(wp0 + (KS) * 32);           \
        WREG[1] = *(const bf16x8*)(wp1 + (KS) * 32);           \
        WREG[2] = *(const bf16x8*)(wp2 + (KS) * 32);           \
        WREG[3] = *(const bf16x8*)(wp3 + (KS) * 32);

        f32x4 acc[4][4];
#pragma unroll
        for (int i = 0; i < 4; ++i)
#pragma unroll
            for (int j = 0; j < 4; ++j) acc[i][j] = (f32x4){0.f, 0.f, 0.f, 0.f};

        // K-step within chunk: row mt*16+lc; logical granule g0 = ks*8+lr*2,
        // physical = g ^ (lc&7)  (row&7 == lc&7)
#define GSTEP(SLOT, KS, WREG)                                                  \
        {                                                                      \
            bf16x8 af[4];                                                      \
            _Pragma("unroll")                                                  \
            for (int mt = 0; mt < 4; ++mt) {                                   \
                const int row = mt * 16 + lc;                                  \
                const int g0 = (KS) * 8 + lr * 2;                              \
                const f32x4 fa = *(const f32x4*)&Xs[SLOT][row * 64 +           \
                                      ((g0 ^ (lc & 7)) << 2)];                 \
                const f32x4 fb = *(const f32x4*)&Xs[SLOT][row * 64 +           \
                                      (((g0 + 1) ^ (lc & 7)) << 2)];           \
                af[mt][0] = (bf16_t)fa[0]; af[mt][1] = (bf16_t)fa[1];          \
                af[mt][2] = (bf16_t)fa[2]; af[mt][3] = (bf16_t)fa[3];          \
                af[mt][4] = (bf16_t)fb[0]; af[mt][5] = (bf16_t)fb[1];          \
                af[mt][6] = (bf16_t)fb[2]; af[mt][7] = (bf16_t)fb[3];          \
            }                                                                  \
            _Pragma("unroll")                                                  \
            for (int mt = 0; mt < 4; ++mt)                                     \
                _Pragma("unroll")                                              \
                for (int ntl = 0; ntl < 4; ++ntl)                              \
                    acc[mt][ntl] = __builtin_amdgcn_mfma_f32_16x16x32_bf16(    \
                        af[mt], WREG[ntl], acc[mt][ntl], 0, 0, 0);             \
        }

        WLOAD(wA, 0);
#pragma unroll
        for (int s = 0; s < 8; ++s) {
            const int slot = s & 3;
#pragma unroll
            for (int p = 0; p < 4; ++p)
                while (__hip_atomic_load(&ready[slot][p], __ATOMIC_ACQUIRE,
                                         __HIP_MEMORY_SCOPE_WORKGROUP) < s) {}
            WLOAD(wB, s * 2 + 1);
            GSTEP(slot, 0, wA);
            if (s < 7) { WLOAD(wA, s * 2 + 2); }
            GSTEP(slot, 1, wB);
            __hip_atomic_store(&done[slot][w], s, __ATOMIC_RELEASE,
                               __HIP_MEMORY_SCOPE_WORKGROUP);
        }
#undef GSTEP
#undef WLOAD

        // epilogue: row = tile*64 + mt*16 + lr*4 + j, col = w*64 + ntl*16 + lc
#pragma unroll
        for (int mt = 0; mt < 4; ++mt) {
#pragma unroll
            for (int ntl = 0; ntl < 4; ++ntl) {
                const int col = w * 64 + ntl * 16 + lc;
#pragma unroll
                for (int j = 0; j < 4; ++j) {
                    const size_t row = rbase + mt * 16 + lr * 4 + j;
                    out[row * 512 + 256 + col] = acc[mt][ntl][j];
                }
            }
        }
    }
}

// ---------------------------------------------------------------------------
// Kernel 2: per-batch attention (EXACT round-8 body, passing).
// ---------------------------------------------------------------------------
__global__ __launch_bounds__(256) void pv_kernel(const int* __restrict__ Adj,
                                                 const float* __restrict__ avec,
                                                 float* __restrict__ out) {
    __shared__ __align__(16) bf16_t hT[256 * HSTR];
    __shared__ __align__(16) bf16_t alp[80 * ASTR];
    __shared__ float a0s[F1], a1s[F1];
    __shared__ float attp0[4][80], attp1[4][80];
    __shared__ float att0s[80], att1s[80], rsums[80];
    __shared__ u64 adjb[160];

    const int b = blockIdx.x;
    const int t = threadIdx.x;
    const int w = t >> 6;
    const int l = t & 63;
    const int lc = l & 15;
    const int lr = l >> 4;
    float* outb = out + (size_t)b * NN * 512;

    a0s[t] = avec[t];
    a1s[t] = avec[F1 + t];
    for (int i = w; i < NN; i += 4) {
        const int v0 = Adj[i * NN + l];
        const int v1 = (l < NN - 64) ? Adj[i * NN + 64 + l] : 0;
        const u64 b0 = __ballot(v0 != 0);
        const u64 b1 = __ballot(v1 != 0);
        if (l == 0) { adjb[i * 2] = b0; adjb[i * 2 + 1] = b1; }
    }
    {
        int* z = (int*)&hT[t * HSTR + 80];
#pragma unroll
        for (int k = 0; k < 8; ++k) z[k] = 0;
    }
    __syncthreads();

    const int c0 = w * 64 + lc * 4;
    const float4 a04 = *(const float4*)&a0s[c0];
    const float4 a14 = *(const float4*)&a1s[c0];
#pragma unroll
    for (int jp = 0; jp < 5; ++jp) {
        const int j0 = jp * 16 + lr * 4;
        float hr[4][4];
#pragma unroll
        for (int r = 0; r < 4; ++r) {
            if (j0 + r < NN) {
                const float4 v = *(const float4*)(outb + (size_t)(j0 + r) * 512 + 256 + c0);
                hr[r][0] = v.x; hr[r][1] = v.y; hr[r][2] = v.z; hr[r][3] = v.w;
            } else {
                hr[r][0] = hr[r][1] = hr[r][2] = hr[r][3] = 0.f;
            }
        }
        float p0[4], p1[4];
#pragma unroll
        for (int r = 0; r < 4; ++r) {
            p0[r] = hr[r][0] * a04.x + hr[r][1] * a04.y + hr[r][2] * a04.z + hr[r][3] * a04.w;
            p1[r] = hr[r][0] * a14.x + hr[r][1] * a14.y + hr[r][2] * a14.z + hr[r][3] * a14.w;
        }
#pragma unroll
        for (int off = 1; off < 16; off <<= 1) {
#pragma unroll
            for (int r = 0; r < 4; ++r) {
                p0[r] += __shfl_xor(p0[r], off);
                p1[r] += __shfl_xor(p1[r], off);
            }
        }
        if (lc == 0) {
#pragma unroll
            for (int r = 0; r < 4; ++r) {
                attp0[w][j0 + r] = p0[r];
                attp1[w][j0 + r] = p1[r];
            }
        }
#pragma unroll
        for (int cc = 0; cc < 4; ++cc) {
            bf16x4_t v;
            v[0] = (bf16_t)hr[0][cc]; v[1] = (bf16_t)hr[1][cc];
            v[2] = (bf16_t)hr[2][cc]; v[3] = (bf16_t)hr[3][cc];
            *(bf16x4_t*)&hT[(c0 + cc) * HSTR + j0] = v;
        }
    }
    __syncthreads();

    if (t < 80)
        att0s[t] = attp0[0][t] + attp0[1][t] + attp0[2][t] + attp0[3][t];
    else if (t < 160)
        att1s[t - 80] = attp1[0][t - 80] + attp1[1][t - 80] + attp1[2][t - 80] + attp1[3][t - 80];
    else if (t < 240) {
        const int r = t - 160;
        if (r < NN) {
            for (int c = NN; c < 96; ++c) alp[r * ASTR + c] = (bf16_t)0.f;
        } else {
            for (int c = 0; c < 96; ++c) alp[r * ASTR + c] = (bf16_t)0.f;
        }
    }
    __syncthreads();

    {
        const int gid = t >> 2;
        const int k4 = t & 3;
#pragma unroll
        for (int r = 0; r < 2; ++r) {
            const int i = r * 64 + gid;
            if (i < NN) {
                const float a0i = att0s[i];
                const u64 w0 = adjb[i * 2];
                const u64 w1 = adjb[i * 2 + 1];
                float e[19];
                float m = -3.0e38f;
#pragma unroll
                for (int jj = 0; jj < 19; ++jj) {
                    const int j = jj * 4 + k4;
                    float ev = -3.0e38f;
                    if (j < NN) {
                        float x = a0i + att1s[j];
                        x = x > 0.f ? x : 0.2f * x;
                        const u64 wj = (j < 64) ? w0 : w1;
                        const int bit = (int)((wj >> (j & 63)) & 1);
                        ev = bit ? x : x - 1.0e9f;
                    }
                    e[jj] = ev;
                    m = fmaxf(m, ev);
                }
                m = fmaxf(m, __shfl_xor(m, 1));
                m = fmaxf(m, __shfl_xor(m, 2));
                float s = 0.f;
#pragma unroll
                for (int jj = 0; jj < 19; ++jj) {
                    const int j = jj * 4 + k4;
                    if (j < NN) {
                        const float ex = __expf(e[jj] - m);
                        s += ex;
                        alp[i * ASTR + j] = (bf16_t)ex;
                    }
                }
                s += __shfl_xor(s, 1);
                s += __shfl_xor(s, 2);
                if (k4 == 0) rsums[i] = 1.f / s;
            }
        }
    }
    __syncthreads();

    f32x4 acc2[5][4];
#pragma unroll
    for (int i = 0; i < 5; ++i)
#pragma unroll
        for (int j = 0; j < 4; ++j) acc2[i][j] = (f32x4){0.f, 0.f, 0.f, 0.f};

#pragma unroll
    for (int ks = 0; ks < 3; ++ks) {
        bf16x8 bv[4];
#pragma unroll
        for (int ntl = 0; ntl < 4; ++ntl) {
            const bf16_t* q = &hT[(w * 64 + ntl * 16 + lc) * HSTR + ks * 32 + lr * 8];
            ((uint2*)&bv[ntl])[0] = *(const uint2*)q;
            ((uint2*)&bv[ntl])[1] = *(const uint2*)(q + 4);
        }
#pragma unroll
        for (int mt = 0; mt < 5; ++mt) {
            const bf16_t* ap = &alp[(mt * 16 + lc) * ASTR + ks * 32 + lr * 8];
            bf16x8 av;
            ((uint2*)&av)[0] = *(const uint2*)ap;
            ((uint2*)&av)[1] = *(const uint2*)(ap + 4);
#pragma unroll
            for (int ntl = 0; ntl < 4; ++ntl)
                acc2[mt][ntl] = __builtin_amdgcn_mfma_f32_16x16x32_bf16(av, bv[ntl], acc2[mt][ntl], 0, 0, 0);
        }
    }

#pragma unroll
    for (int mt = 0; mt < 5; ++mt) {
#pragma unroll
        for (int j = 0; j < 4; ++j) {
            const int row = mt * 16 + lr * 4 + j;
            if (row < NN) {
                const float rsv = rsums[row];
#pragma unroll
                for (int ntl = 0; ntl < 4; ++ntl) {
                    const int ch = w * 64 + ntl * 16 + lc;
                    outb[(size_t)row * 512 + ch] = acc2[mt][ntl][j] * rsv;
                }
            }
        }
    }
}

// ---------------------------------------------------------------------------
extern "C" void kernel_launch(void* const* d_in, const int* in_sizes, int n_in,
                              void* d_out, int out_size, void* d_ws, size_t ws_size,
                              hipStream_t stream) {
    const float* X = (const float*)d_in[0];   // [1024,75,512] f32
    const int*   A = (const int*)d_in[1];     // [75,75] i32
    const float* W = (const float*)d_in[2];   // [512,256] f32
    const float* a = (const float*)d_in[3];   // [2,256,1] f32
    float* out = (float*)d_out;               // [1024,75,512] f32
    bf16_t* Wt = (bf16_t*)d_ws;               // 256 KB scratch

    wt_kernel<<<dim3(KF / 64, F1 / 64), 256, 0, stream>>>(W, Wt);
    gemm_kernel<<<(NB * NN) / 64, 512, 0, stream>>>(X, Wt, out);
    pv_kernel<<<NB, 256, 0, stream>>>(A, a, out);
}

// Round 22
// 125.267 us; speedup vs baseline: 1.1015x; 1.1015x over previous
//
#include <hip/hip_runtime.h>
#include <hip/hip_bf16.h>
#include <math.h>

typedef __bf16 bf16_t;
typedef __bf16 bf16x4_t __attribute__((ext_vector_type(4)));
typedef __bf16 bf16x8 __attribute__((ext_vector_type(8)));
typedef float f32x4 __attribute__((ext_vector_type(4)));
typedef unsigned long long u64;

typedef __attribute__((address_space(1))) const unsigned int cu32_g;
typedef __attribute__((address_space(3))) unsigned int u32_s;

#define NB 1024
#define NN 75
#define KF 512
#define F1 256
#define HSTR 100
#define ASTR 100
#define NT 1200     // gemm tiles (BM=64)
#define GRID 512    // persistent gemm blocks

// ---------------------------------------------------------------------------
// Kernel 0: W [512][256] fp32 -> Wt [256][512] bf16 (unchanged, passing)
// ---------------------------------------------------------------------------
__global__ __launch_bounds__(256) void wt_kernel(const float* __restrict__ W,
                                                 bf16_t* __restrict__ Wt) {
    __shared__ float tile[64][65];
    const int kb = blockIdx.x * 64;
    const int nb = blockIdx.y * 64;
    const int tc = threadIdx.x & 63;
    const int tr = threadIdx.x >> 6;
#pragma unroll
    for (int r = tr; r < 64; r += 4)
        tile[r][tc] = W[(size_t)(kb + r) * F1 + nb + tc];
    __syncthreads();
#pragma unroll
    for (int r = tr; r < 64; r += 4)
        Wt[(size_t)(nb + r) * KF + kb + tc] = (bf16_t)tile[tc][r];
}

// ---------------------------------------------------------------------------
// Kernel 1: h = X @ W -> out[...,256:512].  TILE-STREAMED DMA PIPELINE.
// (round-20 best: gemm ~96 us, total 125.0 us, passed)
// 512 persistent blocks x 2-3 tiles. Per chunk (64 rows x 128 k fp32, 32KB):
//   issue 8 global_load_lds (next chunk -> other buf)   [DMA in flight...]
//   compute 4 K-steps from current buf (cvt fp32->bf16 at read, XOR swizzle)
//   asm vmcnt(0); raw s_barrier                         [...through compute]
// Loads are in flight during ~all wall time. W via r10 register dbuf (L2).
// ---------------------------------------------------------------------------
__global__ __launch_bounds__(256, 2) void gemm_kernel(const float* __restrict__ X,
                                                      const bf16_t* __restrict__ Wt,
                                                      float* __restrict__ out) {
    __shared__ __align__(16) float Xs[2][64 * 128];   // 2 x 32 KB

    const int t = threadIdx.x;
    const int w = t >> 6;
    const int l = t & 63;
    const int lc = l & 15;
    const int lr = l >> 4;

    // W fragment pointers (wave w owns cols w*64 .. w*64+63) — r10 proven
    const bf16_t* wp0 = Wt + (size_t)(w * 64 +  0 + lc) * KF + lr * 8;
    const bf16_t* wp1 = Wt + (size_t)(w * 64 + 16 + lc) * KF + lr * 8;
    const bf16_t* wp2 = Wt + (size_t)(w * 64 + 32 + lc) * KF + lr * 8;
    const bf16_t* wp3 = Wt + (size_t)(w * 64 + 48 + lc) * KF + lr * 8;
    bf16x8 wA[4], wB[4];
#define WLOAD(WREG, KS)                                        \
    WREG[0] = *(const bf16x8*)(wp0 + (KS) * 32);               \
    WREG[1] = *(const bf16x8*)(wp1 + (KS) * 32);               \
    WREG[2] = *(const bf16x8*)(wp2 + (KS) * 32);               \
    WREG[3] = *(const bf16x8*)(wp3 + (KS) * 32);

    // DMA staging: instr u (0..7): lane l -> row u*8 + w*2 + (l>>5),
    // physical 16B-slot l&31 holds logical chunk (l&31)^(row&7) (rule #21:
    // linear LDS dest, inverse-swizzled SOURCE, swizzled read).
    const int sl31 = l & 31;
#define ISSUE(BUF, TILE, C)                                                    \
    {                                                                          \
        _Pragma("unroll")                                                      \
        for (int u = 0; u < 8; ++u) {                                          \
            const int rowl = u * 8 + w * 2 + (l >> 5);                         \
            const float* g = X + ((size_t)(TILE) * 64 + rowl) * KF             \
                              + (C) * 128 + ((sl31 ^ (rowl & 7)) << 2);        \
            float* lp = &Xs[BUF][(u * 8 + w * 2) * 128];                       \
            __builtin_amdgcn_global_load_lds((cu32_g*)g, (u32_s*)lp, 16, 0, 0);\
        }                                                                      \
    }

    f32x4 acc[4][4];

    // compute one K-step: row mt*16+lc, logical slot s0=(KS&3)*8+lr*2,
    // physical = logical ^ (lc&7)
#define GSTEP(BUF, KS, WREG)                                                   \
    {                                                                          \
        bf16x8 af[4];                                                          \
        _Pragma("unroll")                                                      \
        for (int mt = 0; mt < 4; ++mt) {                                       \
            const int row = mt * 16 + lc;                                      \
            const int s0 = ((KS) & 3) * 8 + lr * 2;                            \
            const f32x4 fa = *(const f32x4*)&Xs[BUF][row * 128 +               \
                                                 ((s0 ^ (lc & 7)) << 2)];      \
            const f32x4 fb = *(const f32x4*)&Xs[BUF][row * 128 +               \
                                                 (((s0 + 1) ^ (lc & 7)) << 2)];\
            af[mt][0] = (bf16_t)fa[0]; af[mt][1] = (bf16_t)fa[1];              \
            af[mt][2] = (bf16_t)fa[2]; af[mt][3] = (bf16_t)fa[3];              \
            af[mt][4] = (bf16_t)fb[0]; af[mt][5] = (bf16_t)fb[1];              \
            af[mt][6] = (bf16_t)fb[2]; af[mt][7] = (bf16_t)fb[3];              \
        }                                                                      \
        _Pragma("unroll")                                                      \
        for (int mt = 0; mt < 4; ++mt)                                         \
            _Pragma("unroll")                                                  \
            for (int ntl = 0; ntl < 4; ++ntl)                                  \
                acc[mt][ntl] = __builtin_amdgcn_mfma_f32_16x16x32_bf16(        \
                    af[mt], WREG[ntl], acc[mt][ntl], 0, 0, 0);                 \
    }

#define FENCE_SWAP()                                                           \
    asm volatile("s_waitcnt vmcnt(0)" ::: "memory");                           \
    __builtin_amdgcn_s_barrier();                                              \
    __builtin_amdgcn_sched_barrier(0);

    // chunk body: C = 0..3 (compile-time), cur buf = C&1
#define CHUNK(C, TILE)                                                         \
    {                                                                          \
        if ((C) < 3) {                                                         \
            ISSUE(((C) + 1) & 1, TILE, (C) + 1);                               \
        } else if ((TILE) + GRID < NT) {                                       \
            ISSUE(0, (TILE) + GRID, 0);                                        \
        }                                                                      \
        __builtin_amdgcn_sched_barrier(0);                                     \
        WLOAD(wB, (C) * 4 + 1);                                                \
        GSTEP((C) & 1, (C) * 4 + 0, wA);                                       \
        WLOAD(wA, (C) * 4 + 2);                                                \
        GSTEP((C) & 1, (C) * 4 + 1, wB);                                       \
        WLOAD(wB, (C) * 4 + 3);                                                \
        GSTEP((C) & 1, (C) * 4 + 2, wA);                                       \
        WLOAD(wA, ((C) * 4 + 4) & 15);                                         \
        GSTEP((C) & 1, (C) * 4 + 3, wB);                                       \
        FENCE_SWAP();                                                          \
    }

    // ---- prologue ----
    WLOAD(wA, 0);
    int tile = blockIdx.x;
    ISSUE(0, tile, 0);
    FENCE_SWAP();

    // ---- persistent tile loop ----
    while (tile < NT) {
#pragma unroll
        for (int i = 0; i < 4; ++i)
#pragma unroll
            for (int j = 0; j < 4; ++j) acc[i][j] = (f32x4){0.f, 0.f, 0.f, 0.f};

        CHUNK(0, tile);
        CHUNK(1, tile);
        CHUNK(2, tile);
        CHUNK(3, tile);

        // epilogue: D row = mt*16 + lr*4 + j, col = w*64 + ntl*16 + lc
        const int m0 = tile * 64;
#pragma unroll
        for (int mt = 0; mt < 4; ++mt) {
#pragma unroll
            for (int ntl = 0; ntl < 4; ++ntl) {
                const int col = w * 64 + ntl * 16 + lc;
#pragma unroll
                for (int j = 0; j < 4; ++j) {
                    const int row = m0 + mt * 16 + lr * 4 + j;
                    out[(size_t)row * 512 + 256 + col] = acc[mt][ntl][j];
                }
            }
        }
        tile += GRID;
    }
#undef CHUNK
#undef FENCE_SWAP
#undef GSTEP
#undef ISSUE
#undef WLOAD
}

// ---------------------------------------------------------------------------
// Kernel 2: per-batch attention (EXACT round-8 body, passing).
// ---------------------------------------------------------------------------
__global__ __launch_bounds__(256) void pv_kernel(const int* __restrict__ Adj,
                                                 const float* __restrict__ avec,
                                                 float* __restrict__ out) {
    __shared__ __align__(16) bf16_t hT[256 * HSTR];
    __shared__ __align__(16) bf16_t alp[80 * ASTR];
    __shared__ float a0s[F1], a1s[F1];
    __shared__ float attp0[4][80], attp1[4][80];
    __shared__ float att0s[80], att1s[80], rsums[80];
    __shared__ u64 adjb[160];

    const int b = blockIdx.x;
    const int t = threadIdx.x;
    const int w = t >> 6;
    const int l = t & 63;
    const int lc = l & 15;
    const int lr = l >> 4;
    float* outb = out + (size_t)b * NN * 512;

    a0s[t] = avec[t];
    a1s[t] = avec[F1 + t];
    for (int i = w; i < NN; i += 4) {
        const int v0 = Adj[i * NN + l];
        const int v1 = (l < NN - 64) ? Adj[i * NN + 64 + l] : 0;
        const u64 b0 = __ballot(v0 != 0);
        const u64 b1 = __ballot(v1 != 0);
        if (l == 0) { adjb[i * 2] = b0; adjb[i * 2 + 1] = b1; }
    }
    {
        int* z = (int*)&hT[t * HSTR + 80];
#pragma unroll
        for (int k = 0; k < 8; ++k) z[k] = 0;
    }
    __syncthreads();

    const int c0 = w * 64 + lc * 4;
    const float4 a04 = *(const float4*)&a0s[c0];
    const float4 a14 = *(const float4*)&a1s[c0];
#pragma unroll
    for (int jp = 0; jp < 5; ++jp) {
        const int j0 = jp * 16 + lr * 4;
        float hr[4][4];
#pragma unroll
        for (int r = 0; r < 4; ++r) {
            if (j0 + r < NN) {
                const float4 v = *(const float4*)(outb + (size_t)(j0 + r) * 512 + 256 + c0);
                hr[r][0] = v.x; hr[r][1] = v.y; hr[r][2] = v.z; hr[r][3] = v.w;
            } else {
                hr[r][0] = hr[r][1] = hr[r][2] = hr[r][3] = 0.f;
            }
        }
        float p0[4], p1[4];
#pragma unroll
        for (int r = 0; r < 4; ++r) {
            p0[r] = hr[r][0] * a04.x + hr[r][1] * a04.y + hr[r][2] * a04.z + hr[r][3] * a04.w;
            p1[r] = hr[r][0] * a14.x + hr[r][1] * a14.y + hr[r][2] * a14.z + hr[r][3] * a14.w;
        }
#pragma unroll
        for (int off = 1; off < 16; off <<= 1) {
#pragma unroll
            for (int r = 0; r < 4; ++r) {
                p0[r] += __shfl_xor(p0[r], off);
                p1[r] += __shfl_xor(p1[r], off);
            }
        }
        if (lc == 0) {
#pragma unroll
            for (int r = 0; r < 4; ++r) {
                attp0[w][j0 + r] = p0[r];
                attp1[w][j0 + r] = p1[r];
            }
        }
#pragma unroll
        for (int cc = 0; cc < 4; ++cc) {
            bf16x4_t v;
            v[0] = (bf16_t)hr[0][cc]; v[1] = (bf16_t)hr[1][cc];
            v[2] = (bf16_t)hr[2][cc]; v[3] = (bf16_t)hr[3][cc];
            *(bf16x4_t*)&hT[(c0 + cc) * HSTR + j0] = v;
        }
    }
    __syncthreads();

    if (t < 80)
        att0s[t] = attp0[0][t] + attp0[1][t] + attp0[2][t] + attp0[3][t];
    else if (t < 160)
        att1s[t - 80] = attp1[0][t - 80] + attp1[1][t - 80] + attp1[2][t - 80] + attp1[3][t - 80];
    else if (t < 240) {
        const int r = t - 160;
        if (r < NN) {
            for (int c = NN; c < 96; ++c) alp[r * ASTR + c] = (bf16_t)0.f;
        } else {
            for (int c = 0; c < 96; ++c) alp[r * ASTR + c] = (bf16_t)0.f;
        }
    }
    __syncthreads();

    {
        const int gid = t >> 2;
        const int k4 = t & 3;
#pragma unroll
        for (int r = 0; r < 2; ++r) {
            const int i = r * 64 + gid;
            if (i < NN) {
                const float a0i = att0s[i];
                const u64 w0 = adjb[i * 2];
                const u64 w1 = adjb[i * 2 + 1];
                float e[19];
                float m = -3.0e38f;
#pragma unroll
                for (int jj = 0; jj < 19; ++jj) {
                    const int j = jj * 4 + k4;
                    float ev = -3.0e38f;
                    if (j < NN) {
                        float x = a0i + att1s[j];
                        x = x > 0.f ? x : 0.2f * x;
                        const u64 wj = (j < 64) ? w0 : w1;
                        const int bit = (int)((wj >> (j & 63)) & 1);
                        ev = bit ? x : x - 1.0e9f;
                    }
                    e[jj] = ev;
                    m = fmaxf(m, ev);
                }
                m = fmaxf(m, __shfl_xor(m, 1));
                m = fmaxf(m, __shfl_xor(m, 2));
                float s = 0.f;
#pragma unroll
                for (int jj = 0; jj < 19; ++jj) {
                    const int j = jj * 4 + k4;
                    if (j < NN) {
                        const float ex = __expf(e[jj] - m);
                        s += ex;
                        alp[i * ASTR + j] = (bf16_t)ex;
                    }
                }
                s += __shfl_xor(s, 1);
                s += __shfl_xor(s, 2);
                if (k4 == 0) rsums[i] = 1.f / s;
            }
        }
    }
    __syncthreads();

    f32x4 acc2[5][4];
#pragma unroll
    for (int i = 0; i < 5; ++i)
#pragma unroll
        for (int j = 0; j < 4; ++j) acc2[i][j] = (f32x4){0.f, 0.f, 0.f, 0.f};

#pragma unroll
    for (int ks = 0; ks < 3; ++ks) {
        bf16x8 bv[4];
#pragma unroll
        for (int ntl = 0; ntl < 4; ++ntl) {
            const bf16_t* q = &hT[(w * 64 + ntl * 16 + lc) * HSTR + ks * 32 + lr * 8];
            ((uint2*)&bv[ntl])[0] = *(const uint2*)q;
            ((uint2*)&bv[ntl])[1] = *(const uint2*)(q + 4);
        }
#pragma unroll
        for (int mt = 0; mt < 5; ++mt) {
            const bf16_t* ap = &alp[(mt * 16 + lc) * ASTR + ks * 32 + lr * 8];
            bf16x8 av;
            ((uint2*)&av)[0] = *(const uint2*)ap;
            ((uint2*)&av)[1] = *(const uint2*)(ap + 4);
#pragma unroll
            for (int ntl = 0; ntl < 4; ++ntl)
                acc2[mt][ntl] = __builtin_amdgcn_mfma_f32_16x16x32_bf16(av, bv[ntl], acc2[mt][ntl], 0, 0, 0);
        }
    }

#pragma unroll
    for (int mt = 0; mt < 5; ++mt) {
#pragma unroll
        for (int j = 0; j < 4; ++j) {
            const int row = mt * 16 + lr * 4 + j;
            if (row < NN) {
                const float rsv = rsums[row];
#pragma unroll
                for (int ntl = 0; ntl < 4; ++ntl) {
                    const int ch = w * 64 + ntl * 16 + lc;
                    outb[(size_t)row * 512 + ch] = acc2[mt][ntl][j] * rsv;
                }
            }
        }
    }
}

// ---------------------------------------------------------------------------
extern "C" void kernel_launch(void* const* d_in, const int* in_sizes, int n_in,
                              void* d_out, int out_size, void* d_ws, size_t ws_size,
                              hipStream_t stream) {
    const float* X = (const float*)d_in[0];   // [1024,75,512] f32
    const int*   A = (const int*)d_in[1];     // [75,75] i32
    const float* W = (const float*)d_in[2];   // [512,256] f32
    const float* a = (const float*)d_in[3];   // [2,256,1] f32
    float* out = (float*)d_out;               // [1024,75,512] f32
    bf16_t* Wt = (bf16_t*)d_ws;               // 256 KB scratch

    wt_kernel<<<dim3(KF / 64, F1 / 64), 256, 0, stream>>>(W, Wt);
    gemm_kernel<<<GRID, 256, 0, stream>>>(X, Wt, out);
    pv_kernel<<<NB, 256, 0, stream>>>(A, a, out);
}